// Round 1
// baseline (1140.298 us; speedup 1.0000x reference)
//
#include <hip/hip_runtime.h>
#include <hip/hip_bf16.h>
#include <stdint.h>

// Problem constants (fixed by the reference)
#define BS_N 32768
#define E_DIM 1024
#define H_N 16
#define HD 1024
#define HP 512

typedef __bf16 bf16x8 __attribute__((ext_vector_type(8)));
typedef float f32x4 __attribute__((ext_vector_type(4)));

__device__ __forceinline__ float asf(uint32_t u){ union{uint32_t u;float f;}x; x.u=u; return x.f; }
__device__ __forceinline__ uint32_t asu(float f){ union{float f;uint32_t u;}x; x.f=f; return x.u; }
__device__ __forceinline__ float blo(uint32_t u){ return asf(u<<16); }
__device__ __forceinline__ float bhi(uint32_t u){ return asf(u & 0xffff0000u); }
__device__ __forceinline__ uint16_t f2b(float f){
  uint32_t u = asu(f);
  u = u + 0x7fffu + ((u>>16)&1u);   // round-to-nearest-even
  return (uint16_t)(u>>16);
}
__device__ __forceinline__ uint32_t pack2(float lo, float hi){
  return (uint32_t)f2b(lo) | ((uint32_t)f2b(hi)<<16);
}

// async global->LDS, 16B per lane (dest must be linear: base + lane*16)
#define GLD16(g, l) __builtin_amdgcn_global_load_lds( \
    (__attribute__((address_space(1))) const void*)(g), \
    (__attribute__((address_space(3))) void*)(l), 16, 0, 0)

// ---------------- cast fp32 -> bf16 (vectorized, grid-stride) ----------------
__global__ __launch_bounds__(256) void cast_bf16(const float4* __restrict__ in,
                                                 uint2* __restrict__ out, int n4){
  int i = blockIdx.x*256 + threadIdx.x;
  int stride = gridDim.x*256;
  for (; i < n4; i += stride){
    float4 v = in[i];
    uint2 o; o.x = pack2(v.x, v.y); o.y = pack2(v.z, v.w);
    out[i] = o;
  }
}

// ------------- transpose+cast weights: W[R][C] f32 -> WT[C][R] bf16 ----------
__global__ __launch_bounds__(256) void transpose_cast(const float* __restrict__ W,
                                                      uint16_t* __restrict__ WT,
                                                      int R, int C){
  __shared__ float tile[32][33];
  int c0 = blockIdx.x*32, r0 = blockIdx.y*32;
  int tx = threadIdx.x, ty = threadIdx.y;    // 32 x 8
  #pragma unroll
  for (int i=0;i<32;i+=8) tile[ty+i][tx] = W[(size_t)(r0+ty+i)*C + c0+tx];
  __syncthreads();
  #pragma unroll
  for (int i=0;i<32;i+=8) WT[(size_t)(c0+ty+i)*R + r0+tx] = f2b(tile[tx][ty+i]);
}

// ---- zero-pad attn_bias [BS,16] f32 -> [BS,32] bf16 (K=32 for the GEMM) ----
__global__ __launch_bounds__(256) void prep_ab(const float* __restrict__ ab,
                                               uint16_t* __restrict__ abp){
  int i = blockIdx.x*256 + threadIdx.x;       // over BS*32
  int b = i >> 5, j = i & 31;
  abp[i] = f2b(j < 16 ? ab[b*16 + j] : 0.f);
}

// ---- Wfe [16][512] f32 -> WfeT padded [512][32] bf16 ----
__global__ __launch_bounds__(256) void prep_wfe(const float* __restrict__ Wfe,
                                                uint16_t* __restrict__ WfeTp){
  int i = blockIdx.x*256 + threadIdx.x;       // over 512*32
  int n = i >> 5, j = i & 31;
  float v = (j < 16) ? Wfe[j*512 + n] : 0.f;
  WfeTp[n*32 + j] = f2b(v);
}

// ---------------- bf16 MFMA GEMM, m97 structure --------------------------
// C[M][N] = A[M][K] * BT[N][K]^T + bias[N];  M=32768 fixed, 128x128 tile, BK=32
template<int BF16OUT>
__global__ __launch_bounds__(256) void gemm_bt(const uint16_t* __restrict__ A,
                                               const uint16_t* __restrict__ BT,
                                               const float* __restrict__ bias,
                                               void* __restrict__ Cp,
                                               int N, int K){
  __shared__ alignas(16) uint16_t As[128*32];
  __shared__ alignas(16) uint16_t Bs[128*32];
  const int tid  = threadIdx.x;
  const int lane = tid & 63;
  const int w    = tid >> 6;
  const int wr   = w >> 1, wc = w & 1;

  // XCD-aware swizzle (nwg % 8 == 0 for all our launches); rowTile fastest so
  // each XCD walks one column stripe -> B panel (256KB) L2-resident.
  int bid = (int)blockIdx.x;
  int nwg = (int)gridDim.x;
  int cpx = nwg >> 3;
  int swz = (bid & 7)*cpx + (bid >> 3);
  int rowTile = swz & 255;           // M/128 == 256 always
  int colTile = swz >> 8;
  const size_t row0 = (size_t)rowTile << 7;
  const int col0 = colTile << 7;

  f32x4 acc[4][4];
  #pragma unroll
  for (int m=0;m<4;m++)
    #pragma unroll
    for (int n=0;n<4;n++){ f32x4 z = {0.f,0.f,0.f,0.f}; acc[m][n] = z; }

  // staging: tile = 128 rows x 64B; 512 16B-chunks; thread t takes chunks t, t+256
  const int c0 = tid, c1 = tid + 256;
  const int ar0 = c0 >> 2, ao0 = (c0 & 3) << 4;
  const int ar1 = c1 >> 2, ao1 = (c1 & 3) << 4;
  const size_t K2 = (size_t)K * 2;
  const char* Ab = (const char*)(A  + row0 * (size_t)K);
  const char* Bb = (const char*)(BT + (size_t)col0 * (size_t)K);
  const char* gA0 = Ab + (size_t)ar0*K2 + ao0;
  const char* gA1 = Ab + (size_t)ar1*K2 + ao1;
  const char* gB0 = Bb + (size_t)ar0*K2 + ao0;
  const char* gB1 = Bb + (size_t)ar1*K2 + ao1;
  char* lA0 = (char*)As + c0*16;
  char* lA1 = (char*)As + c1*16;
  char* lB0 = (char*)Bs + c0*16;
  char* lB1 = (char*)Bs + c1*16;

  const int r = lane & 15, kc = lane >> 4;
  const char* aRd = (const char*)As + ((wr<<6) + r)*64 + (kc<<4);
  const char* bRd = (const char*)Bs + ((wc<<6) + r)*64 + (kc<<4);

  for (int kt = 0; kt < K; kt += 32){
    GLD16(gA0 + kt*2, lA0);
    GLD16(gA1 + kt*2, lA1);
    GLD16(gB0 + kt*2, lB0);
    GLD16(gB1 + kt*2, lB1);
    __syncthreads();                       // compiler drains vmcnt(0) here
    bf16x8 a[4], b[4];
    #pragma unroll
    for (int m=0;m<4;m++) a[m] = *(const bf16x8*)(aRd + m*1024);
    #pragma unroll
    for (int n=0;n<4;n++) b[n] = *(const bf16x8*)(bRd + n*1024);
    #pragma unroll
    for (int m=0;m<4;m++)
      #pragma unroll
      for (int n=0;n<4;n++)
        acc[m][n] = __builtin_amdgcn_mfma_f32_16x16x32_bf16(a[m], b[n], acc[m][n], 0, 0, 0);
    __syncthreads();
  }

  // epilogue: C/D layout col=lane&15, row=(lane>>4)*4+j  [m89-verified]
  const int crow = (int)row0 + (wr<<6) + ((lane>>4)<<2);
  const int ccol = col0 + (wc<<6) + (lane & 15);
  #pragma unroll
  for (int n=0;n<4;n++){
    int col = ccol + n*16;
    float bv = bias[col];
    #pragma unroll
    for (int m=0;m<4;m++){
      #pragma unroll
      for (int j=0;j<4;j++){
        float val = acc[m][n][j] + bv;
        if (BF16OUT) ((uint16_t*)Cp)[(size_t)(crow + m*16 + j)*N + col] = f2b(val);
        else         ((float*)Cp)   [(size_t)(crow + m*16 + j)*N + col] = val;
      }
    }
  }
}

// --------- fused middle: qk dot, softmax over P=32, af, t = af*v -----------
__global__ __launch_bounds__(256) void middle(const uint16_t* __restrict__ q,
                                              const uint16_t* __restrict__ k,
                                              const uint16_t* __restrict__ v,
                                              const uint16_t* __restrict__ e,
                                              const uint16_t* __restrict__ f,
                                              const uint16_t* __restrict__ bb,
                                              uint16_t* __restrict__ t){
  int tid = blockIdx.x*256 + threadIdx.x;   // one thread per (b,h)
  int b = tid >> 4, h = tid & 15;
  size_t o64 = ((size_t)b << 10) + (h << 6);
  size_t o32 = ((size_t)b << 9)  + (h << 5);

  const uint4* qp = (const uint4*)(q + o64);
  const uint4* kp = (const uint4*)(k + o64);
  float qk = 0.f;
  #pragma unroll
  for (int i=0;i<8;i++){
    uint4 x = qp[i], y = kp[i];
    qk += blo(x.x)*blo(y.x) + bhi(x.x)*bhi(y.x);
    qk += blo(x.y)*blo(y.y) + bhi(x.y)*bhi(y.y);
    qk += blo(x.z)*blo(y.z) + bhi(x.z)*bhi(y.z);
    qk += blo(x.w)*blo(y.w) + bhi(x.w)*bhi(y.w);
  }
  qk *= 0.125f;                              // 1/sqrt(64)

  const uint4* ep = (const uint4*)(e  + o32);
  const uint4* bp = (const uint4*)(bb + o32);
  float s[32];
  #pragma unroll
  for (int i=0;i<4;i++){
    uint4 ev = ep[i], bv = bp[i];
    s[i*8+0] = qk*blo(ev.x) + blo(bv.x);
    s[i*8+1] = qk*bhi(ev.x) + bhi(bv.x);
    s[i*8+2] = qk*blo(ev.y) + blo(bv.y);
    s[i*8+3] = qk*bhi(ev.y) + bhi(bv.y);
    s[i*8+4] = qk*blo(ev.z) + blo(bv.z);
    s[i*8+5] = qk*bhi(ev.z) + bhi(bv.z);
    s[i*8+6] = qk*blo(ev.w) + blo(bv.w);
    s[i*8+7] = qk*bhi(ev.w) + bhi(bv.w);
  }
  float mx = s[0];
  #pragma unroll
  for (int p=1;p<32;p++) mx = fmaxf(mx, s[p]);
  float sum = 0.f;
  #pragma unroll
  for (int p=0;p<32;p++){ s[p] = __expf(s[p]-mx); sum += s[p]; }

  const uint4* fp = (const uint4*)(f + o32);
  float af = 0.f;
  #pragma unroll
  for (int i=0;i<4;i++){
    uint4 fv = fp[i];
    af += s[i*8+0]*blo(fv.x) + s[i*8+1]*bhi(fv.x);
    af += s[i*8+2]*blo(fv.y) + s[i*8+3]*bhi(fv.y);
    af += s[i*8+4]*blo(fv.z) + s[i*8+5]*bhi(fv.z);
    af += s[i*8+6]*blo(fv.w) + s[i*8+7]*bhi(fv.w);
  }
  af /= sum;

  const uint4* vp = (const uint4*)(v + o64);
  uint4* tp = (uint4*)(t + o64);
  #pragma unroll
  for (int i=0;i<8;i++){
    uint4 vv = vp[i];
    uint4 o;
    o.x = pack2(af*blo(vv.x), af*bhi(vv.x));
    o.y = pack2(af*blo(vv.y), af*bhi(vv.y));
    o.z = pack2(af*blo(vv.z), af*bhi(vv.z));
    o.w = pack2(af*blo(vv.w), af*bhi(vv.w));
    tp[i] = o;
  }
}

extern "C" void kernel_launch(void* const* d_in, const int* in_sizes, int n_in,
                              void* d_out, int out_size, void* d_ws, size_t ws_size,
                              hipStream_t stream){
  const float* query = (const float*)d_in[0];
  const float* key   = (const float*)d_in[1];
  const float* value = (const float*)d_in[2];
  const float* ab    = (const float*)d_in[3];
  const float* Wq  = (const float*)d_in[4];
  const float* bq  = (const float*)d_in[5];
  const float* Wk  = (const float*)d_in[6];
  const float* bk  = (const float*)d_in[7];
  const float* Wv  = (const float*)d_in[8];
  const float* bv  = (const float*)d_in[9];
  const float* We  = (const float*)d_in[10];
  const float* be  = (const float*)d_in[11];
  const float* Wf  = (const float*)d_in[12];
  const float* bfp = (const float*)d_in[13];
  const float* Wfe = (const float*)d_in[14];
  const float* bfe = (const float*)d_in[15];
  const float* Wo  = (const float*)d_in[16];
  const float* bo  = (const float*)d_in[17];

  char* ws = (char*)d_ws;
  const size_t MB = (size_t)1 << 20;
  uint16_t* kb   = (uint16_t*)(ws +   0*MB);  // key   bf16 [BS][1024]
  uint16_t* vb   = (uint16_t*)(ws +  64*MB);  // value bf16
  uint16_t* qb   = (uint16_t*)(ws + 128*MB);  // query bf16 (reused as t)
  uint16_t* qo   = (uint16_t*)(ws + 192*MB);  // q proj
  uint16_t* ko   = (uint16_t*)(ws + 256*MB);  // k proj
  uint16_t* vo   = (uint16_t*)(ws + 320*MB);  // v proj
  uint16_t* eo   = (uint16_t*)(ws + 384*MB);  // e proj [BS][512]
  uint16_t* fo   = (uint16_t*)(ws + 416*MB);  // f proj
  uint16_t* bb   = (uint16_t*)(ws + 448*MB);  // bias   [BS][512]
  uint16_t* abp  = (uint16_t*)(ws + 480*MB);  // padded attn_bias [BS][32]
  uint16_t* WqT  = (uint16_t*)(ws + 482*MB);
  uint16_t* WkT  = (uint16_t*)(ws + 484*MB);
  uint16_t* WvT  = (uint16_t*)(ws + 486*MB);
  uint16_t* WoT  = (uint16_t*)(ws + 488*MB);
  uint16_t* WeT  = (uint16_t*)(ws + 490*MB);
  uint16_t* WfT  = (uint16_t*)(ws + 491*MB);
  uint16_t* WfeTp= (uint16_t*)(ws + 492*MB);
  uint16_t* t    = qb;

  const int n4 = (BS_N*E_DIM)/4;
  cast_bf16<<<2048,256,0,stream>>>((const float4*)query, (uint2*)qb, n4);
  cast_bf16<<<2048,256,0,stream>>>((const float4*)key,   (uint2*)kb, n4);
  cast_bf16<<<2048,256,0,stream>>>((const float4*)value, (uint2*)vb, n4);

  dim3 tb(32,8);
  transpose_cast<<<dim3(32,32),tb,0,stream>>>(Wq, WqT, 1024, 1024);
  transpose_cast<<<dim3(32,32),tb,0,stream>>>(Wk, WkT, 1024, 1024);
  transpose_cast<<<dim3(32,32),tb,0,stream>>>(Wv, WvT, 1024, 1024);
  transpose_cast<<<dim3(32,32),tb,0,stream>>>(Wo, WoT, 1024, 1024);
  transpose_cast<<<dim3(16,32),tb,0,stream>>>(We, WeT, 1024, 512);
  transpose_cast<<<dim3(16,32),tb,0,stream>>>(Wf, WfT, 1024, 512);
  prep_ab<<<4096,256,0,stream>>>(ab, abp);
  prep_wfe<<<64,256,0,stream>>>(Wfe, WfeTp);

  gemm_bt<1><<<2048,256,0,stream>>>(qb,  WqT,   bq,  qo,   1024, 1024);
  gemm_bt<1><<<2048,256,0,stream>>>(kb,  WkT,   bk,  ko,   1024, 1024);
  gemm_bt<1><<<2048,256,0,stream>>>(vb,  WvT,   bv,  vo,   1024, 1024);
  gemm_bt<1><<<1024,256,0,stream>>>(kb,  WeT,   be,  eo,    512, 1024);
  gemm_bt<1><<<1024,256,0,stream>>>(vb,  WfT,   bfp, fo,    512, 1024);
  gemm_bt<1><<<1024,256,0,stream>>>(abp, WfeTp, bfe, bb,    512,   32);

  middle<<<2048,256,0,stream>>>(qo, ko, vo, eo, fo, bb, t);

  gemm_bt<0><<<2048,256,0,stream>>>(t, WoT, bo, d_out, 1024, 1024);
}

// Round 3
// 972.042 us; speedup vs baseline: 1.1731x; 1.1731x over previous
//
#include <hip/hip_runtime.h>
#include <hip/hip_bf16.h>
#include <stdint.h>

#define BS_N 32768
#define E_DIM 1024

typedef __bf16 bf16x8 __attribute__((ext_vector_type(8)));
typedef float f32x4 __attribute__((ext_vector_type(4)));

__device__ __forceinline__ float asf(uint32_t u){ union{uint32_t u;float f;}x; x.u=u; return x.f; }
__device__ __forceinline__ uint32_t asu(float f){ union{float f;uint32_t u;}x; x.f=f; return x.u; }
__device__ __forceinline__ float blo(uint32_t u){ return asf(u<<16); }
__device__ __forceinline__ float bhi(uint32_t u){ return asf(u & 0xffff0000u); }
__device__ __forceinline__ uint16_t f2b(float f){
  uint32_t u = asu(f);
  u = u + 0x7fffu + ((u>>16)&1u);
  return (uint16_t)(u>>16);
}
__device__ __forceinline__ uint32_t pack2(float lo, float hi){
  return (uint32_t)f2b(lo) | ((uint32_t)f2b(hi)<<16);
}

#define GLD16(g, l) __builtin_amdgcn_global_load_lds( \
    (__attribute__((address_space(1))) const void*)(g), \
    (__attribute__((address_space(3))) void*)(l), 16, 0, 0)

#define BAR() __builtin_amdgcn_s_barrier()
#define LGKM0() do{ asm volatile("s_waitcnt lgkmcnt(0)" ::: "memory"); __builtin_amdgcn_sched_barrier(0); }while(0)
#define VMC4() do{ asm volatile("s_waitcnt vmcnt(4)" ::: "memory"); __builtin_amdgcn_sched_barrier(0); }while(0)
#define VMC0() do{ asm volatile("s_waitcnt vmcnt(0)" ::: "memory"); __builtin_amdgcn_sched_barrier(0); }while(0)

// ---------------- cast fp32 -> bf16 ----------------
__global__ __launch_bounds__(256) void cast_bf16(const float4* __restrict__ in,
                                                 uint2* __restrict__ out, int n4){
  int i = blockIdx.x*256 + threadIdx.x;
  int stride = gridDim.x*256;
  for (; i < n4; i += stride){
    float4 v = in[i];
    uint2 o; o.x = pack2(v.x, v.y); o.y = pack2(v.z, v.w);
    out[i] = o;
  }
}

// ------------- transpose+cast weights: W[R][C] f32 -> WT[C][R] bf16 ----------
__global__ __launch_bounds__(256) void transpose_cast(const float* __restrict__ W,
                                                      uint16_t* __restrict__ WT,
                                                      int R, int C){
  __shared__ float tile[32][33];
  int c0 = blockIdx.x*32, r0 = blockIdx.y*32;
  int tx = threadIdx.x, ty = threadIdx.y;    // 32 x 8
  #pragma unroll
  for (int i=0;i<32;i+=8) tile[ty+i][tx] = W[(size_t)(r0+ty+i)*C + c0+tx];
  __syncthreads();
  #pragma unroll
  for (int i=0;i<32;i+=8) WT[(size_t)(c0+ty+i)*R + r0+tx] = f2b(tile[tx][ty+i]);
}

// ---- zero-pad attn_bias [BS,16] f32 -> [BS,32] bf16 ----
__global__ __launch_bounds__(256) void prep_ab(const float* __restrict__ ab,
                                               uint16_t* __restrict__ abp){
  int i = blockIdx.x*256 + threadIdx.x;
  int b = i >> 5, j = i & 31;
  abp[i] = f2b(j < 16 ? ab[b*16 + j] : 0.f);
}

// ---- Wfe [16][512] f32 -> WfeT padded [512][32] bf16 ----
__global__ __launch_bounds__(256) void prep_wfe(const float* __restrict__ Wfe,
                                                uint16_t* __restrict__ WfeTp){
  int i = blockIdx.x*256 + threadIdx.x;
  int n = i >> 5, j = i & 31;
  float v = (j < 16) ? Wfe[j*512 + n] : 0.f;
  WfeTp[n*32 + j] = f2b(v);
}

// ---- concat two bias vectors ----
__global__ __launch_bounds__(256) void cat2(const float* __restrict__ a, int na,
                                            const float* __restrict__ b, int nb,
                                            float* __restrict__ o){
  int i = blockIdx.x*256 + threadIdx.x;
  if (i < na) o[i] = a[i];
  else if (i < na + nb) o[i] = b[i - na];
}

// ================= 256x256 8-phase bf16 MFMA GEMM (T2+T3+T4+T5) ==============
// C[M][N] = A[M][K] * BT[N][K]^T + bias[N]; M=32768 fixed; K%64==0; N%256==0.
// 512 threads = 8 waves (2M x 4N); per-wave C = 128x64; BK=64; LDS 128KB dbuf.
// LDS chunk swizzle (16B chunks, 8/row): stored_chunk = logical_chunk ^ (row&7).
// gld dest linear, source pre-swizzled (rule #21); read XOR-composed (NOT add:
// key bit6 + ks*64 would carry into the row index — round-1 bug, fixed).
// Stage order per K-tile t: p0:A0(t+1) p1:A1(t+1) p2:B0(t+2) p3:B1(t+2);
// gate vmcnt(4) once per tile (leaves B(t+2) in flight).
template<int BF16OUT>
__global__ __launch_bounds__(512, 2) void gemm256(const uint16_t* __restrict__ A,
                                                  const uint16_t* __restrict__ BT,
                                                  const float* __restrict__ bias,
                                                  void* __restrict__ Cp,
                                                  int N, int K){
  __shared__ alignas(16) uint16_t As_[2][16384];   // [buf][256 rows x 64 bf16]
  __shared__ alignas(16) uint16_t Bs_[2][16384];

  const int tid  = threadIdx.x;
  const int lane = tid & 63;
  const int w    = tid >> 6;
  const int wm   = w >> 2;          // 0..1
  const int wn   = w & 3;           // 0..3
  const int r    = lane & 15;
  const int kc   = lane >> 4;

  // XCD swizzle; rowTiles = 32768/256 = 128 fixed; nwg = 128 * colTiles, %8==0
  int bid = (int)blockIdx.x;
  int nwg = (int)gridDim.x;
  int cpx = nwg >> 3;
  int swz = (bid & 7)*cpx + (bid >> 3);
  const int rowTile = swz & 127;
  const int colTile = swz >> 7;
  const int row0 = rowTile << 8;
  const int col0 = colTile << 8;

  f32x4 acc[8][4];
  #pragma unroll
  for (int i=0;i<8;i++)
    #pragma unroll
    for (int j=0;j<4;j++){ f32x4 z = {0.f,0.f,0.f,0.f}; acc[i][j] = z; }

  const int NT = K >> 6;
  const size_t K2 = (size_t)K * 2;

  // staging: dest byte tid*16 within half (linear); source col pre-swizzled
  const int sr  = tid >> 3;                            // row 0..63 within half
  const int scS = ((tid & 7) << 4) ^ ((sr & 7) << 4);  // source col byte
  const char* gA = (const char*)(A  + (size_t)row0 * K) + (size_t)sr*K2 + scS;
  const char* gB = (const char*)(BT + (size_t)col0 * K) + (size_t)sr*K2 + scS;
  char* ldsA = (char*)&As_[0][0];
  char* ldsB = (char*)&Bs_[0][0];

  #define STAGE_A(b, hh, u) do{ \
    const char* s_ = gA + (size_t)(hh)*(K2<<7) + ((size_t)(u)<<7); \
    char* d_ = ldsA + ((b)<<15) + ((hh)<<14) + (tid<<4); \
    GLD16(s_, d_); GLD16(s_ + (K2<<6), d_ + 8192); }while(0)
  #define STAGE_B(b, hh, u) do{ \
    const char* s_ = gB + (size_t)(hh)*(K2<<7) + ((size_t)(u)<<7); \
    char* d_ = ldsB + ((b)<<15) + ((hh)<<14) + (tid<<4); \
    GLD16(s_, d_); GLD16(s_ + (K2<<6), d_ + 8192); }while(0)

  // ds_read: row*128 + ((ks*4+kc) ^ (r&7))*16  == row*128 + (rdKey ^ (ks<<6))
  const int rdKey = (kc << 4) ^ ((r & 7) << 4);        // bits 4-6
  const char* aR = ldsA + ((wm*128 + r) * 128);
  const char* bR = ldsB + ((wn*64  + r) * 128);

  bf16x8 afr[4][2], bf0[2][2], bf1[2][2];

  #define READ_A(QM) do{ \
    _Pragma("unroll") for (int fm=0; fm<4; ++fm) \
    _Pragma("unroll") for (int ks=0; ks<2; ++ks) \
      afr[fm][ks] = *(const bf16x8*)(aB + (QM)*8192 + fm*2048 + (rdKey ^ (ks<<6))); }while(0)
  #define READ_B(DST, QN) do{ \
    _Pragma("unroll") for (int fn=0; fn<2; ++fn) \
    _Pragma("unroll") for (int ks=0; ks<2; ++ks) \
      DST[fn][ks] = *(const bf16x8*)(bB + (QN)*4096 + fn*2048 + (rdKey ^ (ks<<6))); }while(0)
  #define MFMA16(QM, QN, BF) do{ \
    __builtin_amdgcn_s_setprio(1); \
    _Pragma("unroll") for (int ks=0; ks<2; ++ks) \
    _Pragma("unroll") for (int fm=0; fm<4; ++fm) \
    _Pragma("unroll") for (int fn=0; fn<2; ++fn) \
      acc[(QM)*4+fm][(QN)*2+fn] = __builtin_amdgcn_mfma_f32_16x16x32_bf16( \
        afr[fm][ks], BF[fn][ks], acc[(QM)*4+fm][(QN)*2+fn], 0, 0, 0); \
    __builtin_amdgcn_s_setprio(0); }while(0)

  // -------- prologue: tile0 (B,B,A,A), tile1 B halves; gate --------
  STAGE_B(0,0,0); STAGE_B(0,1,0); STAGE_A(0,0,0); STAGE_A(0,1,0);
  if (NT > 1){ STAGE_B(1,0,1); STAGE_B(1,1,1); VMC4(); }
  else       { VMC0(); }
  BAR();

  for (int t = 0; t < NT; ++t){
    const int buf = t & 1;
    const char* aB = aR + (buf << 15);
    const char* bB = bR + (buf << 15);
    // ---- p0: quadrant (0,0) ----
    READ_A(0); READ_B(bf0, 0);
    if (t+1 < NT) STAGE_A(buf^1, 0, t+1);
    BAR(); LGKM0();
    MFMA16(0,0,bf0);
    BAR();
    // ---- p1: quadrant (0,1) ----
    READ_B(bf1, 1);
    if (t+1 < NT) STAGE_A(buf^1, 1, t+1);
    BAR(); LGKM0();
    MFMA16(0,1,bf1);
    BAR();
    // ---- p2: quadrant (1,0) ----
    READ_A(1);
    if (t+2 < NT) STAGE_B(buf, 0, t+2);
    BAR(); LGKM0();
    MFMA16(1,0,bf0);
    BAR();
    // ---- p3: quadrant (1,1) ----
    if (t+2 < NT) STAGE_B(buf, 1, t+2);
    BAR(); LGKM0();
    MFMA16(1,1,bf1);
    if (t+2 < NT) { VMC4(); } else { VMC0(); }
    BAR();
  }

  // -------- epilogue --------
  const int crow = row0 + wm*128 + ((lane>>4)<<2);
  const int ccol = col0 + wn*64 + (lane & 15);
  #pragma unroll
  for (int i=0;i<8;i++){
    #pragma unroll
    for (int n=0;n<4;n++){
      int col = ccol + n*16;
      float bv = bias[col];
      #pragma unroll
      for (int j=0;j<4;j++){
        float val = acc[i][n][j] + bv;
        int row = crow + i*16 + j;
        if (BF16OUT) ((uint16_t*)Cp)[(size_t)row*N + col] = f2b(val);
        else         ((float*)Cp)   [(size_t)row*N + col] = val;
      }
    }
  }
  #undef STAGE_A
  #undef STAGE_B
  #undef READ_A
  #undef READ_B
  #undef MFMA16
}

// ---------------- m97-structure GEMM (kept for the K=32 bias GEMM) -----------
template<int BF16OUT>
__global__ __launch_bounds__(256) void gemm_bt(const uint16_t* __restrict__ A,
                                               const uint16_t* __restrict__ BT,
                                               const float* __restrict__ bias,
                                               void* __restrict__ Cp,
                                               int N, int K){
  __shared__ alignas(16) uint16_t As[128*32];
  __shared__ alignas(16) uint16_t Bs[128*32];
  const int tid  = threadIdx.x;
  const int lane = tid & 63;
  const int w    = tid >> 6;
  const int wr   = w >> 1, wc = w & 1;

  int bid = (int)blockIdx.x;
  int nwg = (int)gridDim.x;
  int cpx = nwg >> 3;
  int swz = (bid & 7)*cpx + (bid >> 3);
  int rowTile = swz & 255;
  int colTile = swz >> 8;
  const size_t row0 = (size_t)rowTile << 7;
  const int col0 = colTile << 7;

  f32x4 acc[4][4];
  #pragma unroll
  for (int m=0;m<4;m++)
    #pragma unroll
    for (int n=0;n<4;n++){ f32x4 z = {0.f,0.f,0.f,0.f}; acc[m][n] = z; }

  const int c0 = tid, c1 = tid + 256;
  const int ar0 = c0 >> 2, ao0 = (c0 & 3) << 4;
  const int ar1 = c1 >> 2, ao1 = (c1 & 3) << 4;
  const size_t K2 = (size_t)K * 2;
  const char* Ab = (const char*)(A  + row0 * (size_t)K);
  const char* Bb = (const char*)(BT + (size_t)col0 * (size_t)K);
  const char* gA0 = Ab + (size_t)ar0*K2 + ao0;
  const char* gA1 = Ab + (size_t)ar1*K2 + ao1;
  const char* gB0 = Bb + (size_t)ar0*K2 + ao0;
  const char* gB1 = Bb + (size_t)ar1*K2 + ao1;
  char* lA0 = (char*)As + c0*16;
  char* lA1 = (char*)As + c1*16;
  char* lB0 = (char*)Bs + c0*16;
  char* lB1 = (char*)Bs + c1*16;

  const int r = lane & 15, kc = lane >> 4;
  const char* aRd = (const char*)As + ((wr<<6) + r)*64 + (kc<<4);
  const char* bRd = (const char*)Bs + ((wc<<6) + r)*64 + (kc<<4);

  for (int kt = 0; kt < K; kt += 32){
    GLD16(gA0 + kt*2, lA0);
    GLD16(gA1 + kt*2, lA1);
    GLD16(gB0 + kt*2, lB0);
    GLD16(gB1 + kt*2, lB1);
    __syncthreads();
    bf16x8 a[4], b[4];
    #pragma unroll
    for (int m=0;m<4;m++) a[m] = *(const bf16x8*)(aRd + m*1024);
    #pragma unroll
    for (int n=0;n<4;n++) b[n] = *(const bf16x8*)(bRd + n*1024);
    #pragma unroll
    for (int m=0;m<4;m++)
      #pragma unroll
      for (int n=0;n<4;n++)
        acc[m][n] = __builtin_amdgcn_mfma_f32_16x16x32_bf16(a[m], b[n], acc[m][n], 0, 0, 0);
    __syncthreads();
  }

  const int crow = (int)row0 + (wr<<6) + ((lane>>4)<<2);
  const int ccol = col0 + (wc<<6) + (lane & 15);
  #pragma unroll
  for (int n=0;n<4;n++){
    int col = ccol + n*16;
    float bv = bias[col];
    #pragma unroll
    for (int m=0;m<4;m++){
      #pragma unroll
      for (int j=0;j<4;j++){
        float val = acc[m][n][j] + bv;
        if (BF16OUT) ((uint16_t*)Cp)[(size_t)(crow + m*16 + j)*N + col] = f2b(val);
        else         ((float*)Cp)   [(size_t)(crow + m*16 + j)*N + col] = val;
      }
    }
  }
}

// --------- fused middle: qk dot, softmax over P=32, af, t = af*v -----------
// layouts: qo [BS][1024]; keo [BS][1536] (k|e); vfo [BS][1536] (v|f); bb [BS][512]
__global__ __launch_bounds__(256) void middle(const uint16_t* __restrict__ qo,
                                              const uint16_t* __restrict__ keo,
                                              const uint16_t* __restrict__ vfo,
                                              const uint16_t* __restrict__ bb,
                                              uint16_t* __restrict__ t){
  int tid = blockIdx.x*256 + threadIdx.x;   // one thread per (b,h)
  int b = tid >> 4, h = tid & 15;

  const uint4* qp = (const uint4*)(qo  + ((size_t)b<<10) + (h<<6));
  const uint4* kp = (const uint4*)(keo + (size_t)b*1536 + (h<<6));
  float qk = 0.f;
  #pragma unroll
  for (int i=0;i<8;i++){
    uint4 x = qp[i], y = kp[i];
    qk += blo(x.x)*blo(y.x) + bhi(x.x)*bhi(y.x);
    qk += blo(x.y)*blo(y.y) + bhi(x.y)*bhi(y.y);
    qk += blo(x.z)*blo(y.z) + bhi(x.z)*bhi(y.z);
    qk += blo(x.w)*blo(y.w) + bhi(x.w)*bhi(y.w);
  }
  qk *= 0.125f;

  const uint4* ep = (const uint4*)(keo + (size_t)b*1536 + 1024 + (h<<5));
  const uint4* bp = (const uint4*)(bb  + ((size_t)b<<9) + (h<<5));
  float s[32];
  #pragma unroll
  for (int i=0;i<4;i++){
    uint4 ev = ep[i], bv = bp[i];
    s[i*8+0] = qk*blo(ev.x) + blo(bv.x);
    s[i*8+1] = qk*bhi(ev.x) + bhi(bv.x);
    s[i*8+2] = qk*blo(ev.y) + blo(bv.y);
    s[i*8+3] = qk*bhi(ev.y) + bhi(bv.y);
    s[i*8+4] = qk*blo(ev.z) + blo(bv.z);
    s[i*8+5] = qk*bhi(ev.z) + bhi(bv.z);
    s[i*8+6] = qk*blo(ev.w) + blo(bv.w);
    s[i*8+7] = qk*bhi(ev.w) + bhi(bv.w);
  }
  float mx = s[0];
  #pragma unroll
  for (int p=1;p<32;p++) mx = fmaxf(mx, s[p]);
  float sum = 0.f;
  #pragma unroll
  for (int p=0;p<32;p++){ s[p] = __expf(s[p]-mx); sum += s[p]; }

  const uint4* fp = (const uint4*)(vfo + (size_t)b*1536 + 1024 + (h<<5));
  float af = 0.f;
  #pragma unroll
  for (int i=0;i<4;i++){
    uint4 fv = fp[i];
    af += s[i*8+0]*blo(fv.x) + s[i*8+1]*bhi(fv.x);
    af += s[i*8+2]*blo(fv.y) + s[i*8+3]*bhi(fv.y);
    af += s[i*8+4]*blo(fv.z) + s[i*8+5]*bhi(fv.z);
    af += s[i*8+6]*blo(fv.w) + s[i*8+7]*bhi(fv.w);
  }
  af /= sum;

  const uint4* vp = (const uint4*)(vfo + (size_t)b*1536 + (h<<6));
  uint4* tp = (uint4*)(t + ((size_t)b<<10) + (h<<6));
  #pragma unroll
  for (int i=0;i<8;i++){
    uint4 vv = vp[i];
    uint4 o;
    o.x = pack2(af*blo(vv.x), af*bhi(vv.x));
    o.y = pack2(af*blo(vv.y), af*bhi(vv.y));
    o.z = pack2(af*blo(vv.z), af*bhi(vv.z));
    o.w = pack2(af*blo(vv.w), af*bhi(vv.w));
    tp[i] = o;
  }
}

extern "C" void kernel_launch(void* const* d_in, const int* in_sizes, int n_in,
                              void* d_out, int out_size, void* d_ws, size_t ws_size,
                              hipStream_t stream){
  const float* query = (const float*)d_in[0];
  const float* key   = (const float*)d_in[1];
  const float* value = (const float*)d_in[2];
  const float* ab    = (const float*)d_in[3];
  const float* Wq  = (const float*)d_in[4];
  const float* bq  = (const float*)d_in[5];
  const float* Wk  = (const float*)d_in[6];
  const float* bk  = (const float*)d_in[7];
  const float* Wv  = (const float*)d_in[8];
  const float* bv  = (const float*)d_in[9];
  const float* We  = (const float*)d_in[10];
  const float* be  = (const float*)d_in[11];
  const float* Wf  = (const float*)d_in[12];
  const float* bfp = (const float*)d_in[13];
  const float* Wfe = (const float*)d_in[14];
  const float* bfe = (const float*)d_in[15];
  const float* Wo  = (const float*)d_in[16];
  const float* bo  = (const float*)d_in[17];

  char* ws = (char*)d_ws;
  const size_t MB = (size_t)1 << 20;
  uint16_t* kb    = (uint16_t*)(ws +   0*MB);  // key   bf16 [BS][1024]
  uint16_t* vb    = (uint16_t*)(ws +  64*MB);  // value bf16
  uint16_t* qb    = (uint16_t*)(ws + 128*MB);  // query bf16 (reused as t)
  uint16_t* qo    = (uint16_t*)(ws + 192*MB);  // q proj [BS][1024]
  uint16_t* keo   = (uint16_t*)(ws + 256*MB);  // k|e    [BS][1536]
  uint16_t* vfo   = (uint16_t*)(ws + 352*MB);  // v|f    [BS][1536]
  uint16_t* bb    = (uint16_t*)(ws + 448*MB);  // bias   [BS][512]
  uint16_t* abp   = (uint16_t*)(ws + 480*MB);  // padded attn_bias [BS][32]
  uint16_t* WqT   = (uint16_t*)(ws + 482*MB);  // [1024][1024]
  uint16_t* WkeT  = (uint16_t*)(ws + 484*MB);  // [1536][1024]
  uint16_t* WvfT  = (uint16_t*)(ws + 487*MB);  // [1536][1024]
  uint16_t* WoT   = (uint16_t*)(ws + 490*MB);  // [1024][1024]
  uint16_t* WfeTp = (uint16_t*)(ws + 492*MB);  // [512][32]
  float*    bke   = (float*)   (ws + 493*MB);  // 1536 f32
  float*    bvf   = (float*)   (ws + 493*MB + 16384);
  uint16_t* t     = qb;

  const int n4 = (BS_N*E_DIM)/4;
  cast_bf16<<<2048,256,0,stream>>>((const float4*)query, (uint2*)qb, n4);
  cast_bf16<<<2048,256,0,stream>>>((const float4*)key,   (uint2*)kb, n4);
  cast_bf16<<<2048,256,0,stream>>>((const float4*)value, (uint2*)vb, n4);

  dim3 tb(32,8);
  transpose_cast<<<dim3(32,32),tb,0,stream>>>(Wq, WqT, 1024, 1024);
  transpose_cast<<<dim3(32,32),tb,0,stream>>>(Wk, WkeT, 1024, 1024);
  transpose_cast<<<dim3(16,32),tb,0,stream>>>(We, WkeT + (size_t)1024*1024, 1024, 512);
  transpose_cast<<<dim3(32,32),tb,0,stream>>>(Wv, WvfT, 1024, 1024);
  transpose_cast<<<dim3(16,32),tb,0,stream>>>(Wf, WvfT + (size_t)1024*1024, 1024, 512);
  transpose_cast<<<dim3(32,32),tb,0,stream>>>(Wo, WoT, 1024, 1024);
  prep_ab<<<4096,256,0,stream>>>(ab, abp);
  prep_wfe<<<64,256,0,stream>>>(Wfe, WfeTp);
  cat2<<<6,256,0,stream>>>(bk, 1024, be, 512, bke);
  cat2<<<6,256,0,stream>>>(bv, 1024, bfp, 512, bvf);

  // big GEMMs on the 8-phase 256^2 kernel
  gemm256<1><<<512,512,0,stream>>>(qb, WqT,  bq,  qo,  1024, 1024);
  gemm256<1><<<768,512,0,stream>>>(kb, WkeT, bke, keo, 1536, 1024);
  gemm256<1><<<768,512,0,stream>>>(vb, WvfT, bvf, vfo, 1536, 1024);

  // tiny bias GEMM (K=32) on the proven m97 kernel
  gemm_bt<1><<<1024,256,0,stream>>>(abp, WfeTp, bfe, bb, 512, 32);

  middle<<<2048,256,0,stream>>>(qo, keo, vfo, bb, t);

  gemm256<0><<<512,512,0,stream>>>(t, WoT, bo, d_out, 1024, 1024);
}